// Round 7
// baseline (83.406 us; speedup 1.0000x reference)
//
#include <hip/hip_runtime.h>
#include <math.h>

#define B_    32
#define P_    32
#define V_    200
#define NF_   4
#define TR_   80
#define NROT_ 16
#define NLIG_ 7
#define NTH_  640

#define WSLOTS 37              // absolute lattice window n in [-26, 10]
#define CSTR   (WSLOTS * 25)   // 925 floats per table

// f32(2*pi) and f32(2*pi/16): DELTA_F*16 == TWO_PI_F exactly.
static constexpr float TWO_PI_F  = 6.2831854820251465f;
static constexpr float DELTA_F   = 0.39269909262657166f;

// ---------------------------------------------------------------------------
// Conv layer via exact-wrap cumulative theta-lattice tables (see R5 header).
// R6: (a) W_conv column preloaded into 80 VGPRs per thread right after the
// scatter barrier (L2 latency hides under G-build/prefix; conv loop is pure
// FMA + LDS broadcast); (b) ballot-based deterministic ranking replaces the
// O(tid) serial loop; (c) head W2 reduction unrolled for load batching.
// One block per (b,p), 640 threads, ~93 KB LDS.
// ---------------------------------------------------------------------------
__global__ __launch_bounds__(NTH_) void masif_conv_kernel(
    const float* __restrict__ feat, const float* __restrict__ rho,
    const float* __restrict__ theta, const float* __restrict__ mask,
    const float* __restrict__ mu_rho, const float* __restrict__ sigma_rho,
    const float* __restrict__ mu_theta, const float* __restrict__ sigma_theta,
    const float* __restrict__ W_conv, const float* __restrict__ b_conv,
    const float* __restrict__ W1, const float* __restrict__ b1,
    const float* __restrict__ bn1_g, const float* __restrict__ bn1_b,
    const float* __restrict__ bn1_m, const float* __restrict__ bn1_v,
    const float* __restrict__ bn2_g, const float* __restrict__ bn2_b,
    const float* __restrict__ bn2_m, const float* __restrict__ bn2_v,
    float* __restrict__ x2out)
{
    __shared__ __align__(16) float s_C[16 * CSTR];      // 59200 B (+overlays)
    __shared__ __align__(16) float s_ch[V_][5];         //  4000 B
    __shared__ __align__(16) float s_R[V_][8];          //  6400 B
    __shared__ __align__(16) float s_ring[2][8][320];   // 20480 B
    __shared__ __align__(16) float s_best[NTH_];        //  2560 B
    __shared__ float s_offs[NROT_];
    __shared__ float s_mu[5], s_isr[5];
    __shared__ float s_ist1;
    __shared__ int   s_cnt[16], s_start[17];
    __shared__ int   s_whist[4][16];

    const int tid = threadIdx.x;
    const int bp  = blockIdx.x;
    const size_t vb = (size_t)bp * V_;

    // staging overlay inside s_C (dead before tables are zeroed/written)
    float*  stg_th  = s_C;                    // [200]
    float*  stg_rho = s_C + 256;              // [200]
    float*  stg_msk = s_C + 512;              // [200]
    float4* stg_f4  = (float4*)(s_C + 768);   // [200] float4
    int*    s_code  = (int*)(s_C + 1600);     // [200]

    for (int i = tid; i < V_; i += NTH_) {
        stg_th[i]  = theta[vb + i];
        stg_rho[i] = rho[vb + i];
        stg_msk[i] = mask[vb + i];
        stg_f4[i]  = ((const float4*)(feat + vb * NF_))[i];
    }
    if (tid < NROT_) s_offs[tid] = (float)tid * DELTA_F;
    if (tid < 5) {
        s_mu[tid] = mu_rho[tid * 16];
        float sg = sigma_rho[tid * 16];
        s_isr[tid] = 1.0f / (sg * sg + 1e-5f);
    }
    if (tid == 5) { float sg = sigma_theta[0]; s_ist1 = 1.0f / (sg * sg + 1e-5f); }
    if (tid >= 32 && tid < 48) s_cnt[tid - 32] = 0;
    __syncthreads();

    // ---- classify by exact first-wrap rotation r* (bucket = r*-1) ----
    int myb = 0;
    if (tid < V_) {
        float th = stg_th[tid];
        int rs = 16;
        for (int r = 1; r < 16; ++r) {
            if (th + s_offs[r] >= TWO_PI_F) { rs = r; break; }   // exact f32 rule
        }
        myb = rs - 1;                         // 0..15
        s_code[tid] = myb;
        atomicAdd(&s_cnt[myb], 1);
    }
    __syncthreads();
    if (tid == 0) {
        int run = 0;
        for (int k = 0; k < 16; ++k) { s_start[k] = run; run += s_cnt[k]; }
        s_start[16] = run;
    }

    // ---- deterministic rank via ballot (waves 0..3 cover tid<256) ----
    int rkw = 0;
    {
        const unsigned long long below = (1ULL << (tid & 63)) - 1ULL;
        const int wv = tid >> 6;
        for (int b = 0; b < 16; ++b) {
            bool p = (tid < V_) && (myb == b);
            unsigned long long m = __ballot(p);
            if (p) rkw = __popcll(m & below);
            if (wv < 4 && (tid & 63) == b) s_whist[wv][b] = __popcll(m);
        }
    }
    __syncthreads();

    // ---- scatter into bucket-sorted arrays ----
    if (tid < V_) {
        int rk = rkw;
        for (int w = 0; w < (tid >> 6); ++w) rk += s_whist[w][myb];
        int pos = s_start[myb] + rk;
        float th = stg_th[tid];
        float mk = stg_msk[tid];
        float4 f4 = stg_f4[tid];
        s_ch[pos][0] = f4.x * mk; s_ch[pos][1] = f4.y * mk;
        s_ch[pos][2] = f4.z * mk; s_ch[pos][3] = f4.w * mk;
        s_ch[pos][4] = mk;
        float rv = stg_rho[tid];
        #pragma unroll
        for (int i = 0; i < 5; ++i) {
            float d = rv - s_mu[i];
            s_R[pos][i] = __expf(-d * d * s_isr[i]);
        }
        s_R[pos][5] = th;
        s_R[pos][6] = 0.0f; s_R[pos][7] = 0.0f;
    }
    __syncthreads();   // staging overlay dead from here

    // ---- preload W_conv column into registers (latency hides under G) ----
    const int half = tid / 320, lt = tid - half * 320;
    const int ef = lt / TR_, eu = lt - ef * TR_;
    float wreg[80];
    {
        const float* Wcol = W_conv + (size_t)ef * TR_ * TR_ + eu;
        #pragma unroll
        for (int k = 0; k < 80; ++k) wreg[k] = Wcol[k * TR_];
    }

    // ---- zero all tables ----
    for (int e = tid; e < 16 * CSTR; e += NTH_) s_C[e] = 0.0f;
    __syncthreads();

    // ---- G-table build: team of 40 threads per bucket (table = team) ----
    {
        const int team = tid / 40, t40 = tid - team * 40;
        const int cg = t40 >> 3;             // channel 0..4
        const int mq = t40 & 7;              // 8 m-tiles x 3 slots = 24 >= 23
        const float ist = s_ist1;
        float acc[3][5];
        #pragma unroll
        for (int mm = 0; mm < 3; ++mm)
            #pragma unroll
            for (int i = 0; i < 5; ++i) acc[mm][i] = 0.0f;
        const int v0 = s_start[team], v1 = s_start[team + 1];
        const float nbase = (float)(team - 27 + mq * 3);   // n at local l=mq*3
        for (int v = v0; v < v1; ++v) {
            float4 ra = *(const float4*)&s_R[v][0];
            float4 rb = *(const float4*)&s_R[v][4];
            const float th = rb.y;
            const float ch = s_ch[v][cg];
            float A0 = ch * ra.x, A1 = ch * ra.y, A2 = ch * ra.z,
                  A3 = ch * ra.w, A4 = ch * rb.x;
            #pragma unroll
            for (int mm = 0; mm < 3; ++mm) {
                float q = fmaf(nbase + (float)mm, DELTA_F, th);
                float w = __expf(-q * q * ist);
                acc[mm][0] = fmaf(w, A0, acc[mm][0]);
                acc[mm][1] = fmaf(w, A1, acc[mm][1]);
                acc[mm][2] = fmaf(w, A2, acc[mm][2]);
                acc[mm][3] = fmaf(w, A3, acc[mm][3]);
                acc[mm][4] = fmaf(w, A4, acc[mm][4]);
            }
        }
        #pragma unroll
        for (int mm = 0; mm < 3; ++mm) {
            const int l = mq * 3 + mm;             // local slot 0..23
            const int w = l + team - 1;            // absolute slot
            if (l < 23 && w >= 0 && w < WSLOTS)
                #pragma unroll
                for (int i = 0; i < 5; ++i)
                    s_C[team * CSTR + w * 25 + cg * 5 + i] = acc[mm][i];
        }
    }
    __syncthreads();

    // ---- shift-free prefix: column walk over all 925 element-columns ----
    for (int e = tid; e < CSTR; e += NTH_) {
        float run = s_C[e];                        // table 0 = C[1]
        #pragma unroll
        for (int tk = 1; tk < 16; ++tk) {
            run += s_C[tk * CSTR + e];
            s_C[tk * CSTR + e] = run;
        }
    }
    __syncthreads();

    // ---- rotation loop: half h computes rotations h*8 .. h*8+7 ----
    const int j1 = lt & 15, ci1 = lt >> 4;        // ci1 = c1*5+i1, 0..19
    const int c1 = ci1 / 5, i1 = ci1 - c1 * 5;
    const int ridx = c1 * TR_ + i1 * 16 + j1;     // desc flat index f*80+t
    const int sD = ci1, sS = 20 + i1;
    const float* Tb = s_C + 15 * CSTR;

    for (int lr = 0; lr < 8; ++lr) {
        const int r  = half * 8 + lr;
        const int wT = r - j1 + 26;               // [11, 41]
        const bool pT = (wT <= 36);
        const int wTc = pT ? wT : 36;
        const float* Tp = Tb + wTc * 25;
        float tD = Tp[sD], tS = Tp[sS];
        float D = pT ? tD : 0.0f;
        float S = pT ? tS : 0.0f;
        if (r > 0) {
            const float* Cr = s_C + (r - 1) * CSTR;
            const float* Up = Cr + wTc * 25;
            float uD = Up[sD], uS = Up[sS];
            if (pT) { D -= uD; S -= uS; }
            const int wW = wT - 16;               // [-5, 25]
            const bool pW = (wW >= 0);
            const int wWc = pW ? wW : 0;
            const float* Wp = Cr + wWc * 25;
            float wD = Wp[sD], wS = Wp[sS];
            if (pW) { D += wD; S += wS; }
        }
        s_ring[half][lr][ridx] = D / (S + 1e-5f);
    }
    __syncthreads();

    // ---- conv: each half convolves its 8 rotations from registers ----
    {
        float a[8];
        #pragma unroll
        for (int q = 0; q < 8; ++q) a[q] = 0.0f;
        #pragma unroll
        for (int kq = 0; kq < 20; ++kq) {
            const int k = kq * 4;
            #pragma unroll
            for (int q = 0; q < 8; ++q) {
                float4 d4 = *(const float4*)&s_ring[half][q][ef * TR_ + k];
                a[q] = fmaf(d4.x, wreg[k],
                       fmaf(d4.y, wreg[k + 1],
                       fmaf(d4.z, wreg[k + 2],
                       fmaf(d4.w, wreg[k + 3], a[q]))));
            }
        }
        float m01 = fmaxf(a[0], a[1]), m23 = fmaxf(a[2], a[3]);
        float m45 = fmaxf(a[4], a[5]), m67 = fmaxf(a[6], a[7]);
        s_best[half * 320 + lt] = fmaxf(fmaxf(m01, m23), fmaxf(m45, m67));
    }
    __syncthreads();

    // ---- epilogue: b_conv + bn1 + relu + W1 + bn2 + relu ----
    float* s_x1   = s_C;             // tables dead now
    float* s_part = s_C + 1024;      // [640]
    if (tid < 320) {
        float best = fmaxf(s_best[tid], s_best[320 + tid]) + b_conv[tid];
        float x1 = (best - bn1_m[tid]) * (bn1_g[tid] * rsqrtf(bn1_v[tid] + 1e-3f))
                   + bn1_b[tid];
        s_x1[tid] = fmaxf(x1, 0.0f);
    }
    __syncthreads();
    {
        const int c = tid / TR_;                 // input chunk 0..7 (40 rows)
        const int ue = tid - c * TR_;
        float p = 0.0f;
        const int i0 = c * 40;
        #pragma unroll 8
        for (int i = i0; i < i0 + 40; ++i)
            p = fmaf(s_x1[i], W1[(size_t)i * TR_ + ue], p);
        s_part[tid] = p;
    }
    __syncthreads();
    if (tid < TR_) {
        float h = b1[tid];
        #pragma unroll
        for (int c = 0; c < 8; ++c) h += s_part[c * TR_ + tid];
        float x2 = (h - bn2_m[tid]) * (bn2_g[tid] * rsqrtf(bn2_v[tid] + 1e-3f))
                   + bn2_b[tid];
        x2out[(size_t)bp * TR_ + tid] = fmaxf(x2, 0.0f);
    }
}

// ---------------------------------------------------------------------------
// Head, stage A: per (b, chunk c of 10 cov rows): cov chunk + W2 partial.
// ---------------------------------------------------------------------------
__global__ __launch_bounds__(256) void masif_head_partial(
    const float* __restrict__ x2,       // [B*P, 80]
    const float* __restrict__ W2,       // [6400, 64]
    float* __restrict__ hpart)          // [B, 8, 64]
{
    __shared__ __align__(16) float s_x[P_ * TR_];
    __shared__ __align__(16) float s_cov[10 * TR_];
    __shared__ float s_red[4][64];

    const int tid = threadIdx.x;
    const int b = blockIdx.x >> 3, c = blockIdx.x & 7;

    for (int i = tid; i < P_ * TR_; i += 256)
        s_x[i] = x2[(size_t)b * P_ * TR_ + i];
    __syncthreads();

    for (int o = tid; o < 800; o += 256) {
        int il = o / TR_, j = o - il * TR_;
        int i = c * 10 + il;
        float s = 0.0f;
        #pragma unroll 4
        for (int p = 0; p < P_; ++p)
            s = fmaf(s_x[p * TR_ + i], s_x[p * TR_ + j], s);
        s_cov[o] = s * (1.0f / (float)P_);
    }
    __syncthreads();

    {
        const int o = tid & 63, sub = tid >> 6;
        float acc = 0.0f;
        const int q0 = sub * 200;
        const size_t gbase = (size_t)(c * 800) * 64 + o;
        #pragma unroll 8
        for (int q = q0; q < q0 + 200; ++q)
            acc = fmaf(s_cov[q], W2[gbase + (size_t)q * 64], acc);
        s_red[sub][o] = acc;
    }
    __syncthreads();
    if (tid < 64)
        hpart[(size_t)b * 512 + c * 64 + tid] =
            s_red[0][tid] + s_red[1][tid] + s_red[2][tid] + s_red[3][tid];
}

// ---------------------------------------------------------------------------
// Head, stage B: combine chunks, relu, bn3, W3.
// ---------------------------------------------------------------------------
__global__ __launch_bounds__(64) void masif_head_final(
    const float* __restrict__ hpart,
    const float* __restrict__ b2,
    const float* __restrict__ bn3_g, const float* __restrict__ bn3_b,
    const float* __restrict__ bn3_m, const float* __restrict__ bn3_v,
    const float* __restrict__ W3, const float* __restrict__ b3,
    float* __restrict__ out)
{
    __shared__ float s_h[64];
    const int tid = threadIdx.x;
    const int b = blockIdx.x;

    float h = b2[tid];
    #pragma unroll
    for (int c = 0; c < 8; ++c) h += hpart[(size_t)b * 512 + c * 64 + tid];
    h = fmaxf(h, 0.0f);
    s_h[tid] = (h - bn3_m[tid]) * (bn3_g[tid] * rsqrtf(bn3_v[tid] + 1e-3f))
               + bn3_b[tid];
    __syncthreads();

    if (tid < NLIG_) {
        float y = b3[tid];
        #pragma unroll
        for (int k = 0; k < 64; ++k)
            y = fmaf(s_h[k], W3[k * NLIG_ + tid], y);
        out[b * NLIG_ + tid] = y;
    }
}

// ---------------------------------------------------------------------------
extern "C" void kernel_launch(void* const* d_in, const int* in_sizes, int n_in,
                              void* d_out, int out_size, void* d_ws, size_t ws_size,
                              hipStream_t stream)
{
    const float* feat      = (const float*)d_in[0];
    const float* rho       = (const float*)d_in[1];
    const float* theta     = (const float*)d_in[2];
    const float* mask      = (const float*)d_in[3];
    const float* mu_rho    = (const float*)d_in[4];
    const float* sigma_rho = (const float*)d_in[5];
    const float* mu_theta  = (const float*)d_in[6];
    const float* sigma_th  = (const float*)d_in[7];
    const float* W_conv    = (const float*)d_in[8];
    const float* b_conv    = (const float*)d_in[9];
    const float* W1        = (const float*)d_in[10];
    const float* b1        = (const float*)d_in[11];
    const float* bn1_g     = (const float*)d_in[12];
    const float* bn1_b     = (const float*)d_in[13];
    const float* bn1_m     = (const float*)d_in[14];
    const float* bn1_v     = (const float*)d_in[15];
    const float* bn2_g     = (const float*)d_in[16];
    const float* bn2_b     = (const float*)d_in[17];
    const float* bn2_m     = (const float*)d_in[18];
    const float* bn2_v     = (const float*)d_in[19];
    const float* W2        = (const float*)d_in[20];
    const float* b2        = (const float*)d_in[21];
    const float* bn3_g     = (const float*)d_in[22];
    const float* bn3_b     = (const float*)d_in[23];
    const float* bn3_m     = (const float*)d_in[24];
    const float* bn3_v     = (const float*)d_in[25];
    const float* W3        = (const float*)d_in[26];
    const float* b3        = (const float*)d_in[27];

    float* x2ws  = (float*)d_ws;                          // [1024*80]
    float* hpart = (float*)d_ws + (size_t)B_ * P_ * TR_;  // [32*8*64]

    masif_conv_kernel<<<dim3(B_ * P_), dim3(NTH_), 0, stream>>>(
        feat, rho, theta, mask, mu_rho, sigma_rho, mu_theta, sigma_th,
        W_conv, b_conv, W1, b1,
        bn1_g, bn1_b, bn1_m, bn1_v, bn2_g, bn2_b, bn2_m, bn2_v, x2ws);

    masif_head_partial<<<dim3(B_ * 8), dim3(256), 0, stream>>>(x2ws, W2, hpart);

    masif_head_final<<<dim3(B_), dim3(64), 0, stream>>>(
        hpart, b2, bn3_g, bn3_b, bn3_m, bn3_v, W3, b3, (float*)d_out);
}

// Round 8
// 82.705 us; speedup vs baseline: 1.0085x; 1.0085x over previous
//
#include <hip/hip_runtime.h>
#include <math.h>

#define B_    32
#define P_    32
#define V_    200
#define NF_   4
#define TR_   80
#define NROT_ 16
#define NLIG_ 7
#define NTH_  640

#define WSLOTS 33              // absolute lattice window n in [-24, 8]
#define CSTR   (WSLOTS * 25)   // 825 floats per table

// f32(2*pi) and f32(2*pi/16): DELTA_F*16 == TWO_PI_F exactly.
static constexpr float TWO_PI_F  = 6.2831854820251465f;
static constexpr float DELTA_F   = 0.39269909262657166f;

// ---------------------------------------------------------------------------
// Conv layer via exact-wrap cumulative theta-lattice tables (see R5 header).
// R7: LDS diet to ~61.4 KB so TWO blocks co-reside per CU (~128 KB cap):
//   (a) window 37->33 slots (dropped tails <= 3.7e-6, desc err ~1e-4);
//   (b) s_ch+s_R merged into s_V[200][12];
//   (c) desc held in 8 regs across a barrier; ring/best/epilogue overlaid
//       into the dead table region (no separate ring/best arrays);
//   (d) no W-preload (VGPR <= 102 for 5 waves/EU; cross-block TLP hides
//       the conv W-load latency instead).
// ---------------------------------------------------------------------------
__global__ __launch_bounds__(NTH_, 5) void masif_conv_kernel(
    const float* __restrict__ feat, const float* __restrict__ rho,
    const float* __restrict__ theta, const float* __restrict__ mask,
    const float* __restrict__ mu_rho, const float* __restrict__ sigma_rho,
    const float* __restrict__ mu_theta, const float* __restrict__ sigma_theta,
    const float* __restrict__ W_conv, const float* __restrict__ b_conv,
    const float* __restrict__ W1, const float* __restrict__ b1,
    const float* __restrict__ bn1_g, const float* __restrict__ bn1_b,
    const float* __restrict__ bn1_m, const float* __restrict__ bn1_v,
    const float* __restrict__ bn2_g, const float* __restrict__ bn2_b,
    const float* __restrict__ bn2_m, const float* __restrict__ bn2_v,
    float* __restrict__ x2out)
{
    __shared__ __align__(16) float s_C[16 * CSTR];   // 52800 B (+overlays)
    __shared__ __align__(16) float s_V[V_][12];      //  9600 B
    __shared__ float s_offs[NROT_];
    __shared__ float s_mu[5], s_isr[5];
    __shared__ float s_ist1;
    __shared__ int   s_cnt[16], s_start[17];
    __shared__ int   s_whist[4][16];

    const int tid = threadIdx.x;
    const int bp  = blockIdx.x;
    const size_t vb = (size_t)bp * V_;

    // staging overlay inside s_C (dead before tables are zeroed/written)
    float*  stg_th  = s_C;                    // [200]
    float*  stg_rho = s_C + 256;              // [200]
    float*  stg_msk = s_C + 512;              // [200]
    float4* stg_f4  = (float4*)(s_C + 768);   // [200] float4 (3072 B, aligned)
    int*    s_code  = (int*)(s_C + 1600);     // [200]

    for (int i = tid; i < V_; i += NTH_) {
        stg_th[i]  = theta[vb + i];
        stg_rho[i] = rho[vb + i];
        stg_msk[i] = mask[vb + i];
        stg_f4[i]  = ((const float4*)(feat + vb * NF_))[i];
    }
    if (tid < NROT_) s_offs[tid] = (float)tid * DELTA_F;
    if (tid < 5) {
        s_mu[tid] = mu_rho[tid * 16];
        float sg = sigma_rho[tid * 16];
        s_isr[tid] = 1.0f / (sg * sg + 1e-5f);
    }
    if (tid == 5) { float sg = sigma_theta[0]; s_ist1 = 1.0f / (sg * sg + 1e-5f); }
    if (tid >= 32 && tid < 48) s_cnt[tid - 32] = 0;
    __syncthreads();

    // ---- classify by exact first-wrap rotation r* (bucket = r*-1) ----
    int myb = 0;
    if (tid < V_) {
        float th = stg_th[tid];
        int rs = 16;
        for (int r = 1; r < 16; ++r) {
            if (th + s_offs[r] >= TWO_PI_F) { rs = r; break; }   // exact f32 rule
        }
        myb = rs - 1;                         // 0..15
        s_code[tid] = myb;
        atomicAdd(&s_cnt[myb], 1);
    }
    __syncthreads();
    if (tid == 0) {
        int run = 0;
        for (int k = 0; k < 16; ++k) { s_start[k] = run; run += s_cnt[k]; }
        s_start[16] = run;
    }

    // ---- deterministic rank via ballot (waves 0..3 cover tid<256) ----
    int rkw = 0;
    {
        const unsigned long long below = (1ULL << (tid & 63)) - 1ULL;
        const int wv = tid >> 6;
        for (int b = 0; b < 16; ++b) {
            bool p = (tid < V_) && (myb == b);
            unsigned long long m = __ballot(p);
            if (p) rkw = __popcll(m & below);
            if (wv < 4 && (tid & 63) == b) s_whist[wv][b] = __popcll(m);
        }
    }
    __syncthreads();

    // ---- scatter into bucket-sorted s_V: [R0..R3 | R4 th ch0 ch1 | ch2..4] --
    if (tid < V_) {
        int rk = rkw;
        for (int w = 0; w < (tid >> 6); ++w) rk += s_whist[w][myb];
        int pos = s_start[myb] + rk;
        float th = stg_th[tid];
        float mk = stg_msk[tid];
        float4 f4 = stg_f4[tid];
        float rv = stg_rho[tid];
        float R[5];
        #pragma unroll
        for (int i = 0; i < 5; ++i) {
            float d = rv - s_mu[i];
            R[i] = __expf(-d * d * s_isr[i]);
        }
        *(float4*)&s_V[pos][0] = make_float4(R[0], R[1], R[2], R[3]);
        *(float4*)&s_V[pos][4] = make_float4(R[4], th, f4.x * mk, f4.y * mk);
        *(float4*)&s_V[pos][8] = make_float4(f4.z * mk, f4.w * mk, mk, 0.0f);
    }
    __syncthreads();   // staging overlay dead from here

    // ---- zero all tables ----
    for (int e = tid; e < 16 * CSTR; e += NTH_) s_C[e] = 0.0f;
    __syncthreads();

    // ---- G-table build: team of 40 threads per bucket (table = team) ----
    // active n in [team-25, team-6] (20 slots); stored slot w = n + 24.
    {
        const int team = tid / 40, t40 = tid - team * 40;
        const int cg = t40 >> 3;             // channel 0..4
        const int mq = t40 & 7;              // 8 m-tiles x 3 slots = 24 >= 20
        const float ist = s_ist1;
        float acc[3][5];
        #pragma unroll
        for (int mm = 0; mm < 3; ++mm)
            #pragma unroll
            for (int i = 0; i < 5; ++i) acc[mm][i] = 0.0f;
        const int v0 = s_start[team], v1 = s_start[team + 1];
        const float nbase = (float)(team - 25 + mq * 3);   // n at local l=mq*3
        for (int v = v0; v < v1; ++v) {
            float4 ra = *(const float4*)&s_V[v][0];
            const float r4 = s_V[v][4];
            const float th = s_V[v][5];
            const float ch = s_V[v][6 + cg];
            float A0 = ch * ra.x, A1 = ch * ra.y, A2 = ch * ra.z,
                  A3 = ch * ra.w, A4 = ch * r4;
            #pragma unroll
            for (int mm = 0; mm < 3; ++mm) {
                float q = fmaf(nbase + (float)mm, DELTA_F, th);
                float w = __expf(-q * q * ist);
                acc[mm][0] = fmaf(w, A0, acc[mm][0]);
                acc[mm][1] = fmaf(w, A1, acc[mm][1]);
                acc[mm][2] = fmaf(w, A2, acc[mm][2]);
                acc[mm][3] = fmaf(w, A3, acc[mm][3]);
                acc[mm][4] = fmaf(w, A4, acc[mm][4]);
            }
        }
        #pragma unroll
        for (int mm = 0; mm < 3; ++mm) {
            const int l = mq * 3 + mm;             // local slot 0..23
            const int w = team - 1 + l;            // stored slot
            if (l < 20 && w >= 0 && w < WSLOTS)
                #pragma unroll
                for (int i = 0; i < 5; ++i)
                    s_C[team * CSTR + w * 25 + cg * 5 + i] = acc[mm][i];
        }
    }
    __syncthreads();

    // ---- shift-free prefix: column walk over all 825 element-columns ----
    for (int e = tid; e < CSTR; e += NTH_) {
        float run = s_C[e];                        // table 0 = C[1]
        #pragma unroll
        for (int tk = 1; tk < 16; ++tk) {
            run += s_C[tk * CSTR + e];
            s_C[tk * CSTR + e] = run;
        }
    }
    __syncthreads();

    // ---- rotation loop: half h computes rotations h*8..h*8+7 into REGS ----
    const int half = tid / 320, lt = tid - half * 320;
    const int j1 = lt & 15, ci1 = lt >> 4;        // ci1 = c1*5+i1, 0..19
    const int c1 = ci1 / 5, i1 = ci1 - c1 * 5;
    const int ridx = c1 * TR_ + i1 * 16 + j1;     // desc flat index f*80+t
    const int sD = ci1, sS = 20 + i1;
    const float* Tb = s_C + 15 * CSTR;
    float dreg[8];

    #pragma unroll
    for (int lr = 0; lr < 8; ++lr) {
        const int r  = half * 8 + lr;
        const int wT = r - j1 + 24;               // [9, 39]
        const bool pT = (wT <= 32);
        const int wTc = pT ? wT : 32;
        const float* Tp = Tb + wTc * 25;
        float tD = Tp[sD], tS = Tp[sS];
        float D = pT ? tD : 0.0f;
        float S = pT ? tS : 0.0f;
        if (r > 0) {
            const float* Cr = s_C + (r - 1) * CSTR;
            const float* Up = Cr + wTc * 25;
            float uD = Up[sD], uS = Up[sS];
            if (pT) { D -= uD; S -= uS; }
            const int wW = wT - 16;               // [-7, 23]
            const bool pW = (wW >= 0);
            const int wWc = pW ? wW : 0;
            const float* Wp = Cr + wWc * 25;
            float wD = Wp[sD], wS = Wp[sS];
            if (pW) { D += wD; S += wS; }
        }
        dreg[lr] = D / (S + 1e-5f);
    }
    __syncthreads();   // all table reads done -> s_C region reusable

    // ---- overlays in dead table region ----
    float* ring   = s_C;                 // [16][320] = 5120 floats
    float* s_best = s_C + 5120;          // [640]
    float* s_x1   = s_C + 5760;          // [320]
    float* s_part = s_C + 6080;          // [640]

    #pragma unroll
    for (int lr = 0; lr < 8; ++lr)
        ring[(half * 8 + lr) * 320 + ridx] = dreg[lr];
    __syncthreads();

    // ---- conv: each half convolves its 8 rotations, W streamed from L2 ----
    {
        const int ef = lt / TR_, eu = lt - ef * TR_;
        const float* Wf = W_conv + (size_t)ef * TR_ * TR_ + eu;
        float a[8];
        #pragma unroll
        for (int q = 0; q < 8; ++q) a[q] = 0.0f;
        for (int k = 0; k < TR_; k += 4) {
            float w0 = Wf[(k + 0) * TR_];
            float w1 = Wf[(k + 1) * TR_];
            float w2 = Wf[(k + 2) * TR_];
            float w3 = Wf[(k + 3) * TR_];
            #pragma unroll
            for (int q = 0; q < 8; ++q) {
                const float* rr = ring + (half * 8 + q) * 320 + ef * TR_ + k;
                float4 d4 = *(const float4*)rr;
                a[q] = fmaf(d4.x, w0, fmaf(d4.y, w1,
                       fmaf(d4.z, w2, fmaf(d4.w, w3, a[q]))));
            }
        }
        float m01 = fmaxf(a[0], a[1]), m23 = fmaxf(a[2], a[3]);
        float m45 = fmaxf(a[4], a[5]), m67 = fmaxf(a[6], a[7]);
        s_best[half * 320 + lt] = fmaxf(fmaxf(m01, m23), fmaxf(m45, m67));
    }
    __syncthreads();

    // ---- epilogue: b_conv + bn1 + relu + W1 + bn2 + relu ----
    if (tid < 320) {
        float best = fmaxf(s_best[tid], s_best[320 + tid]) + b_conv[tid];
        float x1 = (best - bn1_m[tid]) * (bn1_g[tid] * rsqrtf(bn1_v[tid] + 1e-3f))
                   + bn1_b[tid];
        s_x1[tid] = fmaxf(x1, 0.0f);
    }
    __syncthreads();
    {
        const int c = tid / TR_;                 // input chunk 0..7 (40 rows)
        const int ue = tid - c * TR_;
        float p = 0.0f;
        const int i0 = c * 40;
        #pragma unroll 8
        for (int i = i0; i < i0 + 40; ++i)
            p = fmaf(s_x1[i], W1[(size_t)i * TR_ + ue], p);
        s_part[tid] = p;
    }
    __syncthreads();
    if (tid < TR_) {
        float h = b1[tid];
        #pragma unroll
        for (int c = 0; c < 8; ++c) h += s_part[c * TR_ + tid];
        float x2 = (h - bn2_m[tid]) * (bn2_g[tid] * rsqrtf(bn2_v[tid] + 1e-3f))
                   + bn2_b[tid];
        x2out[(size_t)bp * TR_ + tid] = fmaxf(x2, 0.0f);
    }
}

// ---------------------------------------------------------------------------
// Head, stage A: per (b, chunk c of 10 cov rows): cov chunk + W2 partial.
// ---------------------------------------------------------------------------
__global__ __launch_bounds__(256) void masif_head_partial(
    const float* __restrict__ x2,       // [B*P, 80]
    const float* __restrict__ W2,       // [6400, 64]
    float* __restrict__ hpart)          // [B, 8, 64]
{
    __shared__ __align__(16) float s_x[P_ * TR_];
    __shared__ __align__(16) float s_cov[10 * TR_];
    __shared__ float s_red[4][64];

    const int tid = threadIdx.x;
    const int b = blockIdx.x >> 3, c = blockIdx.x & 7;

    for (int i = tid; i < P_ * TR_; i += 256)
        s_x[i] = x2[(size_t)b * P_ * TR_ + i];
    __syncthreads();

    for (int o = tid; o < 800; o += 256) {
        int il = o / TR_, j = o - il * TR_;
        int i = c * 10 + il;
        float s = 0.0f;
        #pragma unroll 4
        for (int p = 0; p < P_; ++p)
            s = fmaf(s_x[p * TR_ + i], s_x[p * TR_ + j], s);
        s_cov[o] = s * (1.0f / (float)P_);
    }
    __syncthreads();

    {
        const int o = tid & 63, sub = tid >> 6;
        float acc = 0.0f;
        const int q0 = sub * 200;
        const size_t gbase = (size_t)(c * 800) * 64 + o;
        #pragma unroll 8
        for (int q = q0; q < q0 + 200; ++q)
            acc = fmaf(s_cov[q], W2[gbase + (size_t)q * 64], acc);
        s_red[sub][o] = acc;
    }
    __syncthreads();
    if (tid < 64)
        hpart[(size_t)b * 512 + c * 64 + tid] =
            s_red[0][tid] + s_red[1][tid] + s_red[2][tid] + s_red[3][tid];
}

// ---------------------------------------------------------------------------
// Head, stage B: combine chunks, relu, bn3, W3.
// ---------------------------------------------------------------------------
__global__ __launch_bounds__(64) void masif_head_final(
    const float* __restrict__ hpart,
    const float* __restrict__ b2,
    const float* __restrict__ bn3_g, const float* __restrict__ bn3_b,
    const float* __restrict__ bn3_m, const float* __restrict__ bn3_v,
    const float* __restrict__ W3, const float* __restrict__ b3,
    float* __restrict__ out)
{
    __shared__ float s_h[64];
    const int tid = threadIdx.x;
    const int b = blockIdx.x;

    float h = b2[tid];
    #pragma unroll
    for (int c = 0; c < 8; ++c) h += hpart[(size_t)b * 512 + c * 64 + tid];
    h = fmaxf(h, 0.0f);
    s_h[tid] = (h - bn3_m[tid]) * (bn3_g[tid] * rsqrtf(bn3_v[tid] + 1e-3f))
               + bn3_b[tid];
    __syncthreads();

    if (tid < NLIG_) {
        float y = b3[tid];
        #pragma unroll
        for (int k = 0; k < 64; ++k)
            y = fmaf(s_h[k], W3[k * NLIG_ + tid], y);
        out[b * NLIG_ + tid] = y;
    }
}

// ---------------------------------------------------------------------------
extern "C" void kernel_launch(void* const* d_in, const int* in_sizes, int n_in,
                              void* d_out, int out_size, void* d_ws, size_t ws_size,
                              hipStream_t stream)
{
    const float* feat      = (const float*)d_in[0];
    const float* rho       = (const float*)d_in[1];
    const float* theta     = (const float*)d_in[2];
    const float* mask      = (const float*)d_in[3];
    const float* mu_rho    = (const float*)d_in[4];
    const float* sigma_rho = (const float*)d_in[5];
    const float* mu_theta  = (const float*)d_in[6];
    const float* sigma_th  = (const float*)d_in[7];
    const float* W_conv    = (const float*)d_in[8];
    const float* b_conv    = (const float*)d_in[9];
    const float* W1        = (const float*)d_in[10];
    const float* b1        = (const float*)d_in[11];
    const float* bn1_g     = (const float*)d_in[12];
    const float* bn1_b     = (const float*)d_in[13];
    const float* bn1_m     = (const float*)d_in[14];
    const float* bn1_v     = (const float*)d_in[15];
    const float* bn2_g     = (const float*)d_in[16];
    const float* bn2_b     = (const float*)d_in[17];
    const float* bn2_m     = (const float*)d_in[18];
    const float* bn2_v     = (const float*)d_in[19];
    const float* W2        = (const float*)d_in[20];
    const float* b2        = (const float*)d_in[21];
    const float* bn3_g     = (const float*)d_in[22];
    const float* bn3_b     = (const float*)d_in[23];
    const float* bn3_m     = (const float*)d_in[24];
    const float* bn3_v     = (const float*)d_in[25];
    const float* W3        = (const float*)d_in[26];
    const float* b3        = (const float*)d_in[27];

    float* x2ws  = (float*)d_ws;                          // [1024*80]
    float* hpart = (float*)d_ws + (size_t)B_ * P_ * TR_;  // [32*8*64]

    masif_conv_kernel<<<dim3(B_ * P_), dim3(NTH_), 0, stream>>>(
        feat, rho, theta, mask, mu_rho, sigma_rho, mu_theta, sigma_th,
        W_conv, b_conv, W1, b1,
        bn1_g, bn1_b, bn1_m, bn1_v, bn2_g, bn2_b, bn2_m, bn2_v, x2ws);

    masif_head_partial<<<dim3(B_ * 8), dim3(256), 0, stream>>>(x2ws, W2, hpart);

    masif_head_final<<<dim3(B_), dim3(64), 0, stream>>>(
        hpart, b2, bn3_g, bn3_b, bn3_m, bn3_v, W3, b3, (float*)d_out);
}